// Round 21
// baseline (183.042 us; speedup 1.0000x reference)
//
#include <hip/hip_runtime.h>
#include <stdint.h>

typedef __attribute__((ext_vector_type(8))) short short8;
typedef __attribute__((ext_vector_type(4))) float f32x4;

__device__ __forceinline__ uint32_t f2bf1(float f) {
  union { float f; uint32_t u; } c; c.f = f;
  return (c.u + 0x7FFFu + ((c.u >> 16) & 1u)) >> 16;
}
__device__ __forceinline__ uint32_t pack2bf(float lo, float hi) {
  return f2bf1(lo) | (f2bf1(hi) << 16);
}
__device__ __forceinline__ float bflo(uint32_t u) {
  union { uint32_t u; float f; } c; c.u = u << 16; return c.f;
}
__device__ __forceinline__ float bfhi(uint32_t u) {
  union { uint32_t u; float f; } c; c.u = u & 0xFFFF0000u; return c.f;
}

// wf frag layout: chunk (nt, ks) holds, for lane l, W row nt*16+(l&15),
// cols ks*32 + (l>>4)*8 .. +8 (one uint4 per lane).
// xbf: row-major bf16 x, 64 u32 per node.
// ALL scratch lives in d_ws; d_out is write-only for gg_kernel.

// ---------------- zero deg ----------------
__global__ void __launch_bounds__(256) zero_kernel(uint4* __restrict__ p, int n4) {
  int i = blockIdx.x * 256 + threadIdx.x;
  if (i < n4) p[i] = make_uint4(0u, 0u, 0u, 0u);
}

// ---- prep: [0,eB) count+pos x8 | [eB,eB+xB) x->xbf (2 chunks/thread) | wf --
__global__ void __launch_bounds__(256) prep_kernel(
    const int* __restrict__ dst, uint32_t* __restrict__ deg,
    uint32_t* __restrict__ pos,
    const float* __restrict__ x, uint32_t* __restrict__ xbf,
    const float* __restrict__ W, uint32_t* __restrict__ wf,
    int E, int N, int eB, int xB) {
  int b = blockIdx.x;
  int ti = threadIdx.x;
  if (b < eB) {
    int e8 = (b * 256 + ti) * 8;
    if (e8 + 7 < E) {
      int4 da = *reinterpret_cast<const int4*>(dst + e8);
      int4 db = *reinterpret_cast<const int4*>(dst + e8 + 4);
      uint4 pa, pb;
      pa.x = atomicAdd(&deg[da.x], 1u);
      pa.y = atomicAdd(&deg[da.y], 1u);
      pa.z = atomicAdd(&deg[da.z], 1u);
      pa.w = atomicAdd(&deg[da.w], 1u);
      pb.x = atomicAdd(&deg[db.x], 1u);
      pb.y = atomicAdd(&deg[db.y], 1u);
      pb.z = atomicAdd(&deg[db.z], 1u);
      pb.w = atomicAdd(&deg[db.w], 1u);
      *reinterpret_cast<uint4*>(pos + e8) = pa;
      *reinterpret_cast<uint4*>(pos + e8 + 4) = pb;
    } else {
      for (int e = e8; e < E; ++e) pos[e] = atomicAdd(&deg[dst[e]], 1u);
    }
  } else if (b < eB + xB) {
    int n = (b - eB) * 32 + (ti >> 3);   // node
    int c0 = ti & 7;                     // chunks c0 and c0+8
    if (n >= N) return;
    const float* xp0 = x + (size_t)n * 128 + c0 * 8;
    const float* xp1 = x + (size_t)n * 128 + (c0 + 8) * 8;
    float4 f0 = reinterpret_cast<const float4*>(xp0)[0];
    float4 f1 = reinterpret_cast<const float4*>(xp0)[1];
    float4 f2 = reinterpret_cast<const float4*>(xp1)[0];
    float4 f3 = reinterpret_cast<const float4*>(xp1)[1];
    uint4 pka, pkb;
    pka.x = pack2bf(f0.x, f0.y); pka.y = pack2bf(f0.z, f0.w);
    pka.z = pack2bf(f1.x, f1.y); pka.w = pack2bf(f1.z, f1.w);
    pkb.x = pack2bf(f2.x, f2.y); pkb.y = pack2bf(f2.z, f2.w);
    pkb.z = pack2bf(f3.x, f3.y); pkb.w = pack2bf(f3.z, f3.w);
    *reinterpret_cast<uint4*>(xbf + (size_t)n * 64 + c0 * 4) = pka;
    *reinterpret_cast<uint4*>(xbf + (size_t)n * 64 + (c0 + 8) * 4) = pkb;
  } else {
    int ch = (b - eB - xB) * 256 + ti;   // W frag chunk id
    if (ch < 4096) {
      int nt = ch >> 9, ks = (ch >> 6) & 7, lane = ch & 63;
      int rw = nt * 16 + (lane & 15);
      const float* wp = W + (size_t)rw * 256 + ks * 32 + (lane >> 4) * 8;
      float4 f0 = reinterpret_cast<const float4*>(wp)[0];
      float4 f1 = reinterpret_cast<const float4*>(wp)[1];
      uint4 pk;
      pk.x = pack2bf(f0.x, f0.y); pk.y = pack2bf(f0.z, f0.w);
      pk.z = pack2bf(f1.x, f1.y); pk.w = pack2bf(f1.z, f1.w);
      reinterpret_cast<uint4*>(wf)[ch] = pk;
    }
  }
}

// ---------------- scan stage 1: per-1024-chunk exclusive partials -----------
__global__ void __launch_bounds__(256) scan1_kernel(
    const uint32_t* __restrict__ deg, uint32_t* __restrict__ partial,
    uint32_t* __restrict__ bsum, int N) {
  __shared__ uint32_t sm[256];
  int t = threadIdx.x;
  int base = blockIdx.x * 1024 + t * 4;
  uint32_t d0 = 0, d1 = 0, d2 = 0, d3 = 0;
  if (base + 3 < N) {
    uint4 v = *reinterpret_cast<const uint4*>(deg + base);
    d0 = v.x; d1 = v.y; d2 = v.z; d3 = v.w;
  } else {
    if (base + 0 < N) d0 = deg[base + 0];
    if (base + 1 < N) d1 = deg[base + 1];
    if (base + 2 < N) d2 = deg[base + 2];
    if (base + 3 < N) d3 = deg[base + 3];
  }
  uint32_t s4 = d0 + d1 + d2 + d3;
  sm[t] = s4;
  uint32_t v = s4;
  __syncthreads();
  #pragma unroll
  for (int off = 1; off < 256; off <<= 1) {
    uint32_t u = (t >= off) ? sm[t - off] : 0u;
    __syncthreads();
    v += u;
    sm[t] = v;
    __syncthreads();
  }
  uint32_t ex = v - s4;
  if (base + 0 < N) partial[base + 0] = ex;
  if (base + 1 < N) partial[base + 1] = ex + d0;
  if (base + 2 < N) partial[base + 2] = ex + d0 + d1;
  if (base + 3 < N) partial[base + 3] = ex + d0 + d1 + d2;
  if (t == 255) bsum[blockIdx.x] = v;
}

// ---------------- scan stage 2: exclusive scan of block sums ----------------
__global__ void __launch_bounds__(1024) scan2_kernel(
    const uint32_t* __restrict__ bsum, uint32_t* __restrict__ boff, int nb) {
  __shared__ uint32_t sm[1024];
  int t = threadIdx.x;
  uint32_t s = (t < nb) ? bsum[t] : 0u;
  sm[t] = s;
  uint32_t v = s;
  __syncthreads();
  #pragma unroll
  for (int off = 1; off < 1024; off <<= 1) {
    uint32_t u = (t >= off) ? sm[t - off] : 0u;
    __syncthreads();
    v += u;
    sm[t] = v;
    __syncthreads();
  }
  if (t < nb) boff[t] = v - s;
}

// ---------------- CSR fill: no atomics (pos precomputed) --------------------
__global__ void __launch_bounds__(256) fill_kernel(
    const int* __restrict__ src, const int* __restrict__ dst,
    const float* __restrict__ ew, const uint32_t* __restrict__ partial,
    const uint32_t* __restrict__ boff, const uint32_t* __restrict__ pos,
    uint2* __restrict__ pairs, int E) {
  int e = blockIdx.x * 256 + threadIdx.x;
  if (e < E) {
    int d = dst[e];
    union { float f; uint32_t u; } w; w.f = ew[e];
    pairs[partial[d] + boff[d >> 10] + pos[e]] = make_uint2((uint32_t)src[e], w.u);
  }
}

// ------ Fused gather+gemm: wave gathers its 32 nodes -> LDS -> MFMA ---------
// Block = 4 waves = 128 nodes. Wave w owns rows [w*32, w*32+32) of LDS ng
// (wave-private => no barrier). Then the 32-node gemm with A-ng from LDS.
__global__ void __launch_bounds__(256) gg_kernel(
    const uint2* __restrict__ pairs, const uint32_t* __restrict__ partial,
    const uint32_t* __restrict__ boff, const uint32_t* __restrict__ deg,
    const uint32_t* __restrict__ xbf, const uint32_t* __restrict__ wf,
    const float* __restrict__ bias, float* __restrict__ out, int N) {
  __shared__ uint32_t ng[128][68];   // pad 68: 16B-aligned rows, 2-way banks
  int wid = threadIdx.x >> 6;
  int lane = threadIdx.x & 63;
  int node0 = blockIdx.x * 128 + wid * 32;
  if (node0 >= N) return;
  int half = lane >> 5;
  int sl2 = lane & 31;
  int lbase = wid * 32;

  // ---- gather phase: 32 nodes, branchless 4-deep pipeline ----
  for (int j = 0; j < 32; ++j) {
    int n = node0 + j;
    if (n >= N) break;
    uint32_t base = partial[n] + boff[n >> 10];
    int dn = (int)deg[n];
    uint2 mp = (lane < dn) ? pairs[base + lane] : make_uint2(0u, 0u);

    float a0 = 0.f, a1 = 0.f, a2 = 0.f, a3 = 0.f;
    int dcap = dn < 64 ? dn : 64;
    int iters = (dcap + 1) >> 1;
    int itp = (iters + 3) & ~3;
    for (int i = 0; i < itp; i += 4) {
      int k0 = (i + 0) * 2 + half;
      int k1 = (i + 1) * 2 + half;
      int k2 = (i + 2) * 2 + half;
      int k3 = (i + 3) * 2 + half;
      uint32_t s0 = (uint32_t)__shfl((int)mp.x, k0, 64);
      uint32_t s1 = (uint32_t)__shfl((int)mp.x, k1, 64);
      uint32_t s2 = (uint32_t)__shfl((int)mp.x, k2, 64);
      uint32_t s3 = (uint32_t)__shfl((int)mp.x, k3, 64);
      union { uint32_t u; float f; } w0, w1, w2, w3;
      w0.u = (uint32_t)__shfl((int)mp.y, k0, 64);
      w1.u = (uint32_t)__shfl((int)mp.y, k1, 64);
      w2.u = (uint32_t)__shfl((int)mp.y, k2, 64);
      w3.u = (uint32_t)__shfl((int)mp.y, k3, 64);
      uint2 v0 = reinterpret_cast<const uint2*>(xbf + (size_t)s0 * 64)[sl2];
      uint2 v1 = reinterpret_cast<const uint2*>(xbf + (size_t)s1 * 64)[sl2];
      uint2 v2 = reinterpret_cast<const uint2*>(xbf + (size_t)s2 * 64)[sl2];
      uint2 v3 = reinterpret_cast<const uint2*>(xbf + (size_t)s3 * 64)[sl2];
      a0 += w0.f * bflo(v0.x); a1 += w0.f * bfhi(v0.x);
      a2 += w0.f * bflo(v0.y); a3 += w0.f * bfhi(v0.y);
      a0 += w1.f * bflo(v1.x); a1 += w1.f * bfhi(v1.x);
      a2 += w1.f * bflo(v1.y); a3 += w1.f * bfhi(v1.y);
      a0 += w2.f * bflo(v2.x); a1 += w2.f * bfhi(v2.x);
      a2 += w2.f * bflo(v2.y); a3 += w2.f * bfhi(v2.y);
      a0 += w3.f * bflo(v3.x); a1 += w3.f * bfhi(v3.x);
      a2 += w3.f * bflo(v3.y); a3 += w3.f * bfhi(v3.y);
    }
    for (int k = 64 + half; k < dn; k += 2) {   // deg>64 tail (never taken here)
      uint2 p = pairs[base + k];
      union { uint32_t u; float f; } w; w.u = p.y;
      uint2 v = reinterpret_cast<const uint2*>(xbf + (size_t)p.x * 64)[sl2];
      a0 += w.f * bflo(v.x);
      a1 += w.f * bfhi(v.x);
      a2 += w.f * bflo(v.y);
      a3 += w.f * bfhi(v.y);
    }

    a0 += __shfl_xor(a0, 32, 64);
    a1 += __shfl_xor(a1, 32, 64);
    a2 += __shfl_xor(a2, 32, 64);
    a3 += __shfl_xor(a3, 32, 64);

    float ss = a0 * a0 + a1 * a1 + a2 * a2 + a3 * a3;
    ss += __shfl_xor(ss, 1, 64);
    ss += __shfl_xor(ss, 2, 64);
    ss += __shfl_xor(ss, 4, 64);
    ss += __shfl_xor(ss, 8, 64);
    ss += __shfl_xor(ss, 16, 64);
    float scale = 1.0f / fmaxf(sqrtf(ss), 1e-12f);
    if (half == 0) {
      uint2 o;
      o.x = pack2bf(a0 * scale, a1 * scale);
      o.y = pack2bf(a2 * scale, a3 * scale);
      *reinterpret_cast<uint2*>(&ng[lbase + j][2 * sl2]) = o;
    }
  }
  // no __syncthreads: each wave reads only its own LDS rows

  // ---- gemm phase: 32-node tile, A-x from xbf, A-ng from LDS, B from wf ----
  int r = lane & 15;
  int kg = lane >> 4;

  short8 a0f[8], a1f[8];
  {
    int rw0 = node0 + r;       if (rw0 > N - 1) rw0 = N - 1;
    int rw1 = node0 + 16 + r;  if (rw1 > N - 1) rw1 = N - 1;
    const uint32_t* xr0 = xbf + (size_t)rw0 * 64 + kg * 4;
    const uint32_t* xr1 = xbf + (size_t)rw1 * 64 + kg * 4;
    #pragma unroll
    for (int ks = 0; ks < 4; ++ks) {
      a0f[ks] = *reinterpret_cast<const short8*>(xr0 + ks * 16);
      a1f[ks] = *reinterpret_cast<const short8*>(xr1 + ks * 16);
    }
    #pragma unroll
    for (int ks = 0; ks < 4; ++ks) {
      a0f[4 + ks] = *reinterpret_cast<const short8*>(
          &ng[lbase + r][ks * 16 + kg * 4]);
      a1f[4 + ks] = *reinterpret_cast<const short8*>(
          &ng[lbase + 16 + r][ks * 16 + kg * 4]);
    }
  }

  f32x4 acc0[8], acc1[8];
  #pragma unroll
  for (int nt = 0; nt < 8; ++nt) {
    acc0[nt] = (f32x4){0.f, 0.f, 0.f, 0.f};
    acc1[nt] = (f32x4){0.f, 0.f, 0.f, 0.f};
  }

  #pragma unroll
  for (int nt = 0; nt < 8; ++nt) {
    #pragma unroll
    for (int ks = 0; ks < 8; ++ks) {
      short8 bfrag = *reinterpret_cast<const short8*>(
          wf + ((size_t)(nt * 8 + ks) * 64 + lane) * 4);
      acc0[nt] = __builtin_amdgcn_mfma_f32_16x16x32_bf16(a0f[ks], bfrag, acc0[nt], 0, 0, 0);
      acc1[nt] = __builtin_amdgcn_mfma_f32_16x16x32_bf16(a1f[ks], bfrag, acc1[nt], 0, 0, 0);
    }
  }

  float bv[8];
  #pragma unroll
  for (int nt = 0; nt < 8; ++nt) bv[nt] = bias[nt * 16 + r];

  #pragma unroll
  for (int st = 0; st < 2; ++st) {
    f32x4* acc = st ? acc1 : acc0;
    int nodeb = node0 + st * 16;
    #pragma unroll
    for (int reg = 0; reg < 4; ++reg) {
      float ss = 0.f;
      #pragma unroll
      for (int nt = 0; nt < 8; ++nt) {
        float v = acc[nt][reg] + bv[nt];
        acc[nt][reg] = v;
        ss += v * v;
      }
      ss += __shfl_xor(ss, 1, 64);
      ss += __shfl_xor(ss, 2, 64);
      ss += __shfl_xor(ss, 4, 64);
      ss += __shfl_xor(ss, 8, 64);
      float scale = 1.0f / fmaxf(sqrtf(ss), 1e-12f);
      int row = nodeb + kg * 4 + reg;
      if (row < N) {
        float* orow = out + (size_t)row * 128;
        #pragma unroll
        for (int nt = 0; nt < 8; ++nt)
          orow[nt * 16 + r] = acc[nt][reg] * scale;
      }
    }
  }
}

extern "C" void kernel_launch(void* const* d_in, const int* in_sizes, int n_in,
                              void* d_out, int out_size, void* d_ws, size_t ws_size,
                              hipStream_t stream) {
  const float* x    = (const float*)d_in[0];
  const int*   ei   = (const int*)d_in[1];   // [2, E]: row0 = src, row1 = dst
  const float* ew   = (const float*)d_in[2];
  const float* W    = (const float*)d_in[3];
  const float* bias = (const float*)d_in[4];
  float* out = (float*)d_out;

  int N = in_sizes[0] / 128;
  int E = in_sizes[1] / 2;
  const int* src = ei;
  const int* dst = ei + E;
  int nb = (N + 1023) / 1024;

  // ALL buffers in d_ws (d_out is write-only for gg_kernel):
  // wf (16384 u32) | xbf (N*64 u32) | deg[N] | partial[N] | bsum[1024] |
  // boff[1024] | pairs[E] (uint2) | pos[E]
  uint32_t* wf      = (uint32_t*)d_ws;
  uint32_t* xbf     = wf + 16384;
  uint32_t* deg     = xbf + (size_t)N * 64;
  uint32_t* partial = deg + N;
  uint32_t* bsum    = partial + N;
  uint32_t* boff    = bsum + 1024;
  uint2*    pairs   = (uint2*)(boff + 1024);
  uint32_t* pos     = (uint32_t*)(pairs + E);

  int eB = (E + 2047) / 2048;
  int xB = (N + 31) / 32;
  int n4 = (N + 3) / 4;
  zero_kernel<<<(n4 + 255) / 256, 256, 0, stream>>>((uint4*)deg, n4);
  prep_kernel<<<eB + xB + 16, 256, 0, stream>>>(
      dst, deg, pos, x, xbf, W, wf, E, N, eB, xB);
  scan1_kernel<<<nb, 256, 0, stream>>>(deg, partial, bsum, N);
  scan2_kernel<<<1, 1024, 0, stream>>>(bsum, boff, nb);
  fill_kernel<<<(E + 255) / 256, 256, 0, stream>>>(src, dst, ew, partial, boff,
                                                   pos, pairs, E);
  int gB = (N + 127) / 128;
  gg_kernel<<<gB, 256, 0, stream>>>(pairs, partial, boff, deg, xbf, wf,
                                    bias, out, N);
}

// Round 23
// 124.929 us; speedup vs baseline: 1.4652x; 1.4652x over previous
//
#include <hip/hip_runtime.h>
#include <stdint.h>

typedef __attribute__((ext_vector_type(8))) short short8;
typedef __attribute__((ext_vector_type(4))) float f32x4;

__device__ __forceinline__ uint32_t f2bf1(float f) {
  union { float f; uint32_t u; } c; c.f = f;
  return (c.u + 0x7FFFu + ((c.u >> 16) & 1u)) >> 16;
}
__device__ __forceinline__ uint32_t pack2bf(float lo, float hi) {
  return f2bf1(lo) | (f2bf1(hi) << 16);
}
__device__ __forceinline__ float bflo(uint32_t u) {
  union { uint32_t u; float f; } c; c.u = u << 16; return c.f;
}
__device__ __forceinline__ float bfhi(uint32_t u) {
  union { uint32_t u; float f; } c; c.u = u & 0xFFFF0000u; return c.f;
}

// ngf fragment layout: chunk (tile16 t, ks4) holds, for lane l, node
// t*16+(l&15), ng cols (ks4)*32 + (l>>4)*8 .. +8 (one uint4 per lane).
// wf: chunk (nt, ks) same pattern over W rows/cols.
// xbf: row-major bf16 x, 64 u32 per node.

// ---- prep: [0,eB) count+pos x8 | [eB,eB+xB) x->xbf (2 chunks/thread) | wf --
__global__ void __launch_bounds__(256) prep_kernel(
    const int* __restrict__ dst, uint32_t* __restrict__ deg,
    uint32_t* __restrict__ pos,
    const float* __restrict__ x, uint32_t* __restrict__ xbf,
    const float* __restrict__ W, uint32_t* __restrict__ wf,
    int E, int N, int eB, int xB) {
  int b = blockIdx.x;
  int ti = threadIdx.x;
  if (b < eB) {
    int e8 = (b * 256 + ti) * 8;
    if (e8 + 7 < E) {
      int4 da = *reinterpret_cast<const int4*>(dst + e8);
      int4 db = *reinterpret_cast<const int4*>(dst + e8 + 4);
      uint4 pa, pb;
      pa.x = atomicAdd(&deg[da.x], 1u);
      pa.y = atomicAdd(&deg[da.y], 1u);
      pa.z = atomicAdd(&deg[da.z], 1u);
      pa.w = atomicAdd(&deg[da.w], 1u);
      pb.x = atomicAdd(&deg[db.x], 1u);
      pb.y = atomicAdd(&deg[db.y], 1u);
      pb.z = atomicAdd(&deg[db.z], 1u);
      pb.w = atomicAdd(&deg[db.w], 1u);
      *reinterpret_cast<uint4*>(pos + e8) = pa;
      *reinterpret_cast<uint4*>(pos + e8 + 4) = pb;
    } else {
      for (int e = e8; e < E; ++e) pos[e] = atomicAdd(&deg[dst[e]], 1u);
    }
  } else if (b < eB + xB) {
    int n = (b - eB) * 32 + (ti >> 3);   // node
    int c0 = ti & 7;                     // chunks c0 and c0+8
    if (n >= N) return;
    const float* xp0 = x + (size_t)n * 128 + c0 * 8;
    const float* xp1 = x + (size_t)n * 128 + (c0 + 8) * 8;
    float4 f0 = reinterpret_cast<const float4*>(xp0)[0];
    float4 f1 = reinterpret_cast<const float4*>(xp0)[1];
    float4 f2 = reinterpret_cast<const float4*>(xp1)[0];
    float4 f3 = reinterpret_cast<const float4*>(xp1)[1];
    uint4 pka, pkb;
    pka.x = pack2bf(f0.x, f0.y); pka.y = pack2bf(f0.z, f0.w);
    pka.z = pack2bf(f1.x, f1.y); pka.w = pack2bf(f1.z, f1.w);
    pkb.x = pack2bf(f2.x, f2.y); pkb.y = pack2bf(f2.z, f2.w);
    pkb.z = pack2bf(f3.x, f3.y); pkb.w = pack2bf(f3.z, f3.w);
    *reinterpret_cast<uint4*>(xbf + (size_t)n * 64 + c0 * 4) = pka;
    *reinterpret_cast<uint4*>(xbf + (size_t)n * 64 + (c0 + 8) * 4) = pkb;
  } else {
    int ch = (b - eB - xB) * 256 + ti;   // W frag chunk id
    if (ch < 4096) {
      int nt = ch >> 9, ks = (ch >> 6) & 7, lane = ch & 63;
      int rw = nt * 16 + (lane & 15);
      const float* wp = W + (size_t)rw * 256 + ks * 32 + (lane >> 4) * 8;
      float4 f0 = reinterpret_cast<const float4*>(wp)[0];
      float4 f1 = reinterpret_cast<const float4*>(wp)[1];
      uint4 pk;
      pk.x = pack2bf(f0.x, f0.y); pk.y = pack2bf(f0.z, f0.w);
      pk.z = pack2bf(f1.x, f1.y); pk.w = pack2bf(f1.z, f1.w);
      reinterpret_cast<uint4*>(wf)[ch] = pk;
    }
  }
}

// ---------------- scan stage 1: per-1024-chunk exclusive partials -----------
__global__ void __launch_bounds__(256) scan1_kernel(
    const uint32_t* __restrict__ deg, uint32_t* __restrict__ partial,
    uint32_t* __restrict__ bsum, int N) {
  __shared__ uint32_t sm[256];
  int t = threadIdx.x;
  int base = blockIdx.x * 1024 + t * 4;
  uint32_t d0 = 0, d1 = 0, d2 = 0, d3 = 0;
  if (base + 3 < N) {
    uint4 v = *reinterpret_cast<const uint4*>(deg + base);
    d0 = v.x; d1 = v.y; d2 = v.z; d3 = v.w;
  } else {
    if (base + 0 < N) d0 = deg[base + 0];
    if (base + 1 < N) d1 = deg[base + 1];
    if (base + 2 < N) d2 = deg[base + 2];
    if (base + 3 < N) d3 = deg[base + 3];
  }
  uint32_t s4 = d0 + d1 + d2 + d3;
  sm[t] = s4;
  uint32_t v = s4;
  __syncthreads();
  #pragma unroll
  for (int off = 1; off < 256; off <<= 1) {
    uint32_t u = (t >= off) ? sm[t - off] : 0u;
    __syncthreads();
    v += u;
    sm[t] = v;
    __syncthreads();
  }
  uint32_t ex = v - s4;
  if (base + 0 < N) partial[base + 0] = ex;
  if (base + 1 < N) partial[base + 1] = ex + d0;
  if (base + 2 < N) partial[base + 2] = ex + d0 + d1;
  if (base + 3 < N) partial[base + 3] = ex + d0 + d1 + d2;
  if (t == 255) bsum[blockIdx.x] = v;
}

// ---------------- scan stage 2: exclusive scan of block sums ----------------
__global__ void __launch_bounds__(1024) scan2_kernel(
    const uint32_t* __restrict__ bsum, uint32_t* __restrict__ boff, int nb) {
  __shared__ uint32_t sm[1024];
  int t = threadIdx.x;
  uint32_t s = (t < nb) ? bsum[t] : 0u;
  sm[t] = s;
  uint32_t v = s;
  __syncthreads();
  #pragma unroll
  for (int off = 1; off < 1024; off <<= 1) {
    uint32_t u = (t >= off) ? sm[t - off] : 0u;
    __syncthreads();
    v += u;
    sm[t] = v;
    __syncthreads();
  }
  if (t < nb) boff[t] = v - s;
}

// ---------------- CSR fill: no atomics (pos precomputed) --------------------
__global__ void __launch_bounds__(256) fill_kernel(
    const int* __restrict__ src, const int* __restrict__ dst,
    const float* __restrict__ ew, const uint32_t* __restrict__ partial,
    const uint32_t* __restrict__ boff, const uint32_t* __restrict__ pos,
    uint2* __restrict__ pairs, int E) {
  int e = blockIdx.x * 256 + threadIdx.x;
  if (e < E) {
    int d = dst[e];
    union { float f; uint32_t u; } w; w.f = ew[e];
    pairs[partial[d] + boff[d >> 10] + pos[e]] = make_uint2((uint32_t)src[e], w.u);
  }
}

// -- Gather: branchless 4-deep pipeline, 2 edges/slot (half-wave, uint2) -----
// mp zeroed beyond dn => dead slots read row 0 with w=0 (harmless, L1-hot).
__global__ void __launch_bounds__(256) gather_kernel(
    const uint2* __restrict__ pairs, const uint32_t* __restrict__ partial,
    const uint32_t* __restrict__ boff, const uint32_t* __restrict__ deg,
    const uint32_t* __restrict__ xbf, uint32_t* __restrict__ ngf, int N) {
  int n = blockIdx.x * 4 + (threadIdx.x >> 6);
  if (n >= N) return;
  int lane = threadIdx.x & 63;
  int half = lane >> 5;   // edge slot parity
  int sl2 = lane & 31;    // elems 4*sl2 .. 4*sl2+3
  uint32_t base = partial[n] + boff[n >> 10];
  int dn = (int)deg[n];

  uint2 mp = (lane < dn) ? pairs[base + lane] : make_uint2(0u, 0u);

  float a0 = 0.f, a1 = 0.f, a2 = 0.f, a3 = 0.f;
  int dcap = dn < 64 ? dn : 64;
  int iters = (dcap + 1) >> 1;
  int itp = (iters + 3) & ~3;   // padded: dead slots contribute 0
  for (int i = 0; i < itp; i += 4) {
    int k0 = (i + 0) * 2 + half;
    int k1 = (i + 1) * 2 + half;
    int k2 = (i + 2) * 2 + half;
    int k3 = (i + 3) * 2 + half;
    uint32_t s0 = (uint32_t)__shfl((int)mp.x, k0, 64);
    uint32_t s1 = (uint32_t)__shfl((int)mp.x, k1, 64);
    uint32_t s2 = (uint32_t)__shfl((int)mp.x, k2, 64);
    uint32_t s3 = (uint32_t)__shfl((int)mp.x, k3, 64);
    union { uint32_t u; float f; } w0, w1, w2, w3;
    w0.u = (uint32_t)__shfl((int)mp.y, k0, 64);
    w1.u = (uint32_t)__shfl((int)mp.y, k1, 64);
    w2.u = (uint32_t)__shfl((int)mp.y, k2, 64);
    w3.u = (uint32_t)__shfl((int)mp.y, k3, 64);
    // 4 independent row loads in flight
    uint2 v0 = reinterpret_cast<const uint2*>(xbf + (size_t)s0 * 64)[sl2];
    uint2 v1 = reinterpret_cast<const uint2*>(xbf + (size_t)s1 * 64)[sl2];
    uint2 v2 = reinterpret_cast<const uint2*>(xbf + (size_t)s2 * 64)[sl2];
    uint2 v3 = reinterpret_cast<const uint2*>(xbf + (size_t)s3 * 64)[sl2];
    a0 += w0.f * bflo(v0.x); a1 += w0.f * bfhi(v0.x);
    a2 += w0.f * bflo(v0.y); a3 += w0.f * bfhi(v0.y);
    a0 += w1.f * bflo(v1.x); a1 += w1.f * bfhi(v1.x);
    a2 += w1.f * bflo(v1.y); a3 += w1.f * bfhi(v1.y);
    a0 += w2.f * bflo(v2.x); a1 += w2.f * bfhi(v2.x);
    a2 += w2.f * bflo(v2.y); a3 += w2.f * bfhi(v2.y);
    a0 += w3.f * bflo(v3.x); a1 += w3.f * bfhi(v3.x);
    a2 += w3.f * bflo(v3.y); a3 += w3.f * bfhi(v3.y);
  }
  // correctness tail for deg > 64 (statistically never taken here)
  for (int k = 64 + half; k < dn; k += 2) {
    uint2 p = pairs[base + k];
    union { uint32_t u; float f; } w; w.u = p.y;
    uint2 v = reinterpret_cast<const uint2*>(xbf + (size_t)p.x * 64)[sl2];
    a0 += w.f * bflo(v.x);
    a1 += w.f * bfhi(v.x);
    a2 += w.f * bflo(v.y);
    a3 += w.f * bfhi(v.y);
  }

  a0 += __shfl_xor(a0, 32, 64);
  a1 += __shfl_xor(a1, 32, 64);
  a2 += __shfl_xor(a2, 32, 64);
  a3 += __shfl_xor(a3, 32, 64);

  float ss = a0 * a0 + a1 * a1 + a2 * a2 + a3 * a3;
  ss += __shfl_xor(ss, 1, 64);
  ss += __shfl_xor(ss, 2, 64);
  ss += __shfl_xor(ss, 4, 64);
  ss += __shfl_xor(ss, 8, 64);
  ss += __shfl_xor(ss, 16, 64);
  float scale = 1.0f / fmaxf(sqrtf(ss), 1e-12f);
  if (half == 0) {
    uint2 o;
    o.x = pack2bf(a0 * scale, a1 * scale);
    o.y = pack2bf(a2 * scale, a3 * scale);
    // ng elems 4*sl2..+3 -> chunk (n>>4)*4+(sl2>>3),
    // slot kg=(sl2&7)>>1 -> lane_c=kg*16+(n&15), u32 pair j=2*(sl2&1)
    int t = n >> 4, rr = n & 15;
    uint32_t* dstp = ngf +
        ((size_t)(t * 4 + (sl2 >> 3)) * 64 + ((sl2 & 7) >> 1) * 16 + rr) * 4 +
        (sl2 & 1) * 2;
    *reinterpret_cast<uint2*>(dstp) = o;
  }
}

// ---------------- out = normalize(cat @ W^T + b) ----------------------------
// One wave per 32-node tile (two 16-row subtiles sharing each B-frag load).
// A-x frags read per-lane from row-major xbf (16 rows x 64B dense sub-block);
// A-ng frags and B frags are frag-major 1KB bursts.
__global__ void __launch_bounds__(256) gemm_kernel(
    const uint32_t* __restrict__ xbf, const uint32_t* __restrict__ ngf,
    const uint32_t* __restrict__ wf, const float* __restrict__ bias,
    float* __restrict__ out, int N) {
  int wid = threadIdx.x >> 6;
  int lane = threadIdx.x & 63;
  int tile = blockIdx.x * 4 + wid;     // 32-row tile
  int node0 = tile * 32;
  if (node0 >= N) return;
  int r = lane & 15;
  int kg = lane >> 4;
  int t0 = tile * 2;                   // 16-row frag tiles t0, t0+1

  short8 a0[8], a1[8];
  {
    const uint32_t* xr0 = xbf + (size_t)(node0 + r) * 64 + kg * 4;
    const uint32_t* xr1 = xr0 + 16 * 64;
    #pragma unroll
    for (int ks = 0; ks < 4; ++ks) {
      a0[ks] = *reinterpret_cast<const short8*>(xr0 + ks * 16);
      a1[ks] = *reinterpret_cast<const short8*>(xr1 + ks * 16);
    }
    #pragma unroll
    for (int ks = 0; ks < 4; ++ks) {
      a0[4 + ks] = *reinterpret_cast<const short8*>(
          ngf + ((size_t)(t0 * 4 + ks) * 64 + lane) * 4);
      a1[4 + ks] = *reinterpret_cast<const short8*>(
          ngf + ((size_t)((t0 + 1) * 4 + ks) * 64 + lane) * 4);
    }
  }

  f32x4 acc0[8], acc1[8];
  #pragma unroll
  for (int nt = 0; nt < 8; ++nt) {
    acc0[nt] = (f32x4){0.f, 0.f, 0.f, 0.f};
    acc1[nt] = (f32x4){0.f, 0.f, 0.f, 0.f};
  }

  #pragma unroll
  for (int nt = 0; nt < 8; ++nt) {
    #pragma unroll
    for (int ks = 0; ks < 8; ++ks) {
      short8 bfrag = *reinterpret_cast<const short8*>(
          wf + ((size_t)(nt * 8 + ks) * 64 + lane) * 4);
      acc0[nt] = __builtin_amdgcn_mfma_f32_16x16x32_bf16(a0[ks], bfrag, acc0[nt], 0, 0, 0);
      acc1[nt] = __builtin_amdgcn_mfma_f32_16x16x32_bf16(a1[ks], bfrag, acc1[nt], 0, 0, 0);
    }
  }

  float bv[8];
  #pragma unroll
  for (int nt = 0; nt < 8; ++nt) bv[nt] = bias[nt * 16 + r];

  #pragma unroll
  for (int st = 0; st < 2; ++st) {
    f32x4* acc = st ? acc1 : acc0;
    int nodeb = node0 + st * 16;
    #pragma unroll
    for (int reg = 0; reg < 4; ++reg) {
      float ss = 0.f;
      #pragma unroll
      for (int nt = 0; nt < 8; ++nt) {
        float v = acc[nt][reg] + bv[nt];
        acc[nt][reg] = v;
        ss += v * v;
      }
      ss += __shfl_xor(ss, 1, 64);
      ss += __shfl_xor(ss, 2, 64);
      ss += __shfl_xor(ss, 4, 64);
      ss += __shfl_xor(ss, 8, 64);
      float scale = 1.0f / fmaxf(sqrtf(ss), 1e-12f);
      float* orow = out + (size_t)(nodeb + kg * 4 + reg) * 128;
      #pragma unroll
      for (int nt = 0; nt < 8; ++nt)
        orow[nt * 16 + r] = acc[nt][reg] * scale;
    }
  }
}

extern "C" void kernel_launch(void* const* d_in, const int* in_sizes, int n_in,
                              void* d_out, int out_size, void* d_ws, size_t ws_size,
                              hipStream_t stream) {
  const float* x    = (const float*)d_in[0];
  const int*   ei   = (const int*)d_in[1];   // [2, E]: row0 = src, row1 = dst
  const float* ew   = (const float*)d_in[2];
  const float* W    = (const float*)d_in[3];
  const float* bias = (const float*)d_in[4];
  float* out = (float*)d_out;

  int N = in_sizes[0] / 128;
  int E = in_sizes[1] / 2;
  const int* src = ei;
  const int* dst = ei + E;
  int nb = (N + 1023) / 1024;

  // d_ws: ngf (N*64 u32) | wf (16384 u32) | xbf (N*64 u32)
  uint32_t* ngf = (uint32_t*)d_ws;
  uint32_t* wf  = ngf + (size_t)N * 64;
  uint32_t* xbf = wf + 16384;

  // d_out scratch (free until gemm overwrites d_out):
  // deg[N], partial[N], bsum[1024], boff[1024], pairs[E](uint2), pos[E]
  uint32_t* o       = (uint32_t*)d_out;
  uint32_t* deg     = o;
  uint32_t* partial = o + N;
  uint32_t* bsum    = o + 2 * (size_t)N;
  uint32_t* boff    = o + 2 * (size_t)N + 1024;
  uint2*    pairs   = (uint2*)(o + 2 * (size_t)N + 2048);
  uint32_t* pos     = o + 2 * (size_t)N + 2048 + 2 * (size_t)E;

  int eB = (E + 2047) / 2048;
  int xB = (N + 31) / 32;
  hipMemsetAsync(deg, 0, (size_t)N * sizeof(uint32_t), stream);
  prep_kernel<<<eB + xB + 16, 256, 0, stream>>>(
      dst, deg, pos, x, xbf, W, wf, E, N, eB, xB);
  scan1_kernel<<<nb, 256, 0, stream>>>(deg, partial, bsum, N);
  scan2_kernel<<<1, 1024, 0, stream>>>(bsum, boff, nb);
  fill_kernel<<<(E + 255) / 256, 256, 0, stream>>>(src, dst, ew, partial, boff,
                                                   pos, pairs, E);
  gather_kernel<<<(N + 3) / 4, 256, 0, stream>>>(pairs, partial, boff, deg,
                                                 xbf, ngf, N);
  int ntiles32 = (N + 31) / 32;
  gemm_kernel<<<(ntiles32 + 3) / 4, 256, 0, stream>>>(xbf, ngf, wf, bias, out, N);
}